// Round 4
// baseline (105.576 us; speedup 1.0000x reference)
//
#include <hip/hip_runtime.h>

#define S_DIM 20
#define NSTEP 19     // S_DIM - 1 compute steps
#define EMB   64
#define GSTR  72     // uint32 words per ped-row: 0..31 gm_mean bf16, 32..63 H bf16, 64..71 pad (288B, 16B-aligned)
#define MAXP  128

typedef __attribute__((ext_vector_type(8))) short bf16x8;
typedef __attribute__((ext_vector_type(4))) float f32x4;

__device__ __forceinline__ uint32_t pk_bf16(float lo, float hi) {
    uint32_t r;
    asm("v_cvt_pk_bf16_f32 %0, %1, %2" : "=v"(r) : "v"(lo), "v"(hi));
    return r;
}
__device__ __forceinline__ short bf16s(float v) { return (short)(pk_bf16(v, v) & 0xffffu); }
__device__ __forceinline__ float unbf16(uint32_t lo16) {
    union { uint32_t u; float f; } c; c.u = lo16 << 16; return c.f;
}

__global__ __launch_bounds__(256, 4) void pfa_kernel(
    const float* __restrict__ nodes_abs,   // (S,N,2)
    const float* __restrict__ seq_list,    // (S,N)
    const int*   __restrict__ pednum,      // (B)
    const float* __restrict__ W_in,        // (2,EMB)
    const float* __restrict__ W_gm,        // (EMB,EMB)
    const float* __restrict__ b_h,         // (EMB)
    const float* __restrict__ W_out,       // (EMB,2)
    const float* __restrict__ b_out,       // (2)
    float*       __restrict__ out,         // (S,N,2)
    int N, int B)
{
    const int b    = blockIdx.x;
    const int t    = threadIdx.x;
    const int lane = t & 63;
    const int w    = t >> 6;           // 4 waves
    const int l15  = lane & 15;
    const int hi   = lane >> 4;

    __shared__ __attribute__((aligned(16))) uint32_t G[8 * 16 * GSTR];  // 8 row-blocks (wave-private pairs)
    __shared__ uint32_t masks[MAXP];
    __shared__ float2   cxy[NSTEP];

    // ---- scene start: per-wave redundant prefix sum ----
    int partial = 0;
    for (int i = lane; i < b; i += 64) partial += pednum[i];
    #pragma unroll
    for (int off = 32; off; off >>= 1) partial += __shfl_xor(partial, off, 64);
    const int start = partial;
    const int P = min(pednum[b], MAXP);
    const int q = (P + 7) >> 3;        // peds per row-block (8 rb total)

    // ---- zero own G slice (2 rb per wave; wave-private, no barrier) ----
    {
        uint4* g4 = (uint4*)&G[(w * 2) * 16 * GSTR];
        for (int i = lane; i < 2 * 16 * GSTR / 4; i += 64)
            g4[i] = make_uint4(0u, 0u, 0u, 0u);
    }

    // ---- constant A-fragments (registers) ----
    bf16x8 agm[4][2];
    #pragma unroll
    for (int m = 0; m < 4; ++m)
        #pragma unroll
        for (int T = 0; T < 2; ++T)
            #pragma unroll
            for (int e = 0; e < 8; ++e)
                agm[m][T][e] = bf16s(W_gm[(32*T + 8*hi + e) * EMB + 16*m + l15]);

    bf16x8 aaug[4];
    #pragma unroll
    for (int m = 0; m < 4; ++m) {
        bf16x8 a = {0,0,0,0,0,0,0,0};
        if (hi == 0) {
            const int j = 16*m + l15;
            const float w0 = W_in[j], w1 = W_in[EMB + j], bh = b_h[j];
            const short w0h = bf16s(w0); const short w0l = bf16s(w0 - unbf16((uint16_t)w0h));
            const short w1h = bf16s(w1); const short w1l = bf16s(w1 - unbf16((uint16_t)w1h));
            const short bhh = bf16s(bh); const short bhl = bf16s(bh - unbf16((uint16_t)bhh));
            a[0]=w0h; a[1]=w0l; a[2]=w0h; a[3]=w1h; a[4]=w1l; a[5]=w1h; a[6]=bhh; a[7]=bhl;
        }
        aaug[m] = a;
    }

    bf16x8 aout[2];
    #pragma unroll
    for (int T = 0; T < 2; ++T)
        #pragma unroll
        for (int e = 0; e < 8; ++e) {
            const int j = 32*T + 8*hi + e;
            aout[T][e] = (l15 < 2) ? bf16s(W_out[j*2 + l15]) : (short)0;
        }
    const float bo0 = b_out[0], bo1 = b_out[1];

    // ---- Phase 1: per-ped presence bitmask (prefix-AND over steps) ----
    if (t < P) {
        uint32_t m = 0; bool alive = true;
        #pragma unroll
        for (int f = 0; f < NSTEP; ++f) {
            alive = alive && (seq_list[(size_t)f * N + start + t] > 0.0f);
            m |= (alive ? 1u : 0u) << f;
        }
        masks[t] = m;
    }
    __syncthreads();

    // ---- Phase 2: per-step scene centers (wave w handles f = w, w+4, ...) ----
    for (int f = w; f < NSTEP; f += 4) {
        float cnt = 0.f, sx = 0.f, sy = 0.f;
        for (int p = lane; p < P; p += 64) {
            const float mf = (float)((masks[p] >> f) & 1u);
            const float2 a = *(const float2*)&nodes_abs[((size_t)f * N + start + p) * 2];
            cnt += mf; sx = fmaf(a.x, mf, sx); sy = fmaf(a.y, mf, sy);
        }
        #pragma unroll
        for (int off = 32; off; off >>= 1) {
            cnt += __shfl_xor(cnt, off, 64);
            sx  += __shfl_xor(sx , off, 64);
            sy  += __shfl_xor(sy , off, 64);
        }
        if (lane == 0) {
            const float ic = __builtin_amdgcn_rcpf(fmaxf(cnt, 1.0f));
            cxy[f] = make_float2(sx * ic, sy * ic);
        }
    }
    __syncthreads();

    // ---- Phase 3: sequential loop, no barriers / no shuffles ----
    bool     vr[2];
    int      gi[2];
    uint32_t mk[2];
    float2   ab[2];
    #pragma unroll
    for (int r = 0; r < 2; ++r) {
        const int pd = 2*q*w + r*q + l15;
        vr[r] = (l15 < q) && (pd < P);
        gi[r] = start + (vr[r] ? pd : 0);
        mk[r] = vr[r] ? masks[pd] : 0u;
        ab[r] = *(const float2*)&nodes_abs[(size_t)gi[r] * 2];
    }

    f32x4 gm[2][4];
    const f32x4 zero4 = {0.f, 0.f, 0.f, 0.f};
    #pragma unroll
    for (int r = 0; r < 2; ++r)
        #pragma unroll
        for (int m = 0; m < 4; ++m) gm[r][m] = zero4;

    const bool h0 = (hi == 0);

    #pragma unroll 1
    for (int f = 0; f < NSTEP; ++f) {
        const float2 c = cxy[f];
        const float invf2 = __builtin_amdgcn_rcpf((float)(f + 1));   // divisor for NEXT step's gm_mean

        #pragma unroll
        for (int r = 0; r < 2; ++r) {
            uint32_t* const Grow = &G[((w*2 + r) * 16 + l15) * GSTR];
            const float mf  = (float)((mk[r] >> f) & 1u);
            const float cxd = ab[r].x - c.x;
            const float cyd = ab[r].y - c.y;
            // prefetch next step's coords (row f+1 always exists: S_DIM rows)
            ab[r] = *(const float2*)&nodes_abs[((size_t)(f + 1) * N + gi[r]) * 2];

            // aug B-fragment (rows k=0..7 live in hi==0 lanes)
            const uint32_t e0 = pk_bf16(cxd, cxd);
            const float    cxl = cxd - unbf16(e0 & 0xffffu);
            const uint32_t ey = pk_bf16(cyd, cyd);
            const float    cyl = cyd - unbf16(ey & 0xffffu);
            const uint32_t e1 = pk_bf16(cxl, cyd);
            const uint32_t e2 = pk_bf16(cyd, cyl);
            union { uint32_t u[4]; bf16x8 v; } b2u;
            b2u.u[0] = h0 ? e0 : 0u;
            b2u.u[1] = h0 ? e1 : 0u;
            b2u.u[2] = h0 ? e2 : 0u;
            b2u.u[3] = h0 ? 0x3f803f80u : 0u;

            const bf16x8 B0 = *(const bf16x8*)&Grow[ 0 + 4*hi];
            const bf16x8 B1 = *(const bf16x8*)&Grow[16 + 4*hi];

            f32x4 acc[4];
            #pragma unroll
            for (int m = 0; m < 4; ++m) {
                f32x4 cacc = zero4;
                cacc = __builtin_amdgcn_mfma_f32_16x16x32_bf16(aaug[m],   b2u.v, cacc, 0, 0, 0);
                cacc = __builtin_amdgcn_mfma_f32_16x16x32_bf16(agm[m][0], B0,    cacc, 0, 0, 0);
                cacc = __builtin_amdgcn_mfma_f32_16x16x32_bf16(agm[m][1], B1,    cacc, 0, 0, 0);
                acc[m] = cacc;
            }

            // tanh (masked) + gm accumulate + pack h into H region
            const float m2 = -2.0f * mf;
            #pragma unroll
            for (int m = 0; m < 4; ++m) {
                f32x4 h4;
                #pragma unroll
                for (int rr = 0; rr < 4; ++rr) {
                    const float x  = acc[m][rr];
                    const float e  = __expf(2.0f * x);
                    const float tt = __builtin_amdgcn_rcpf(e + 1.0f);
                    h4[rr] = fmaf(tt, m2, mf);          // mf * tanh(x)
                }
                gm[r][m] += h4;
                const uint32_t p0 = pk_bf16(h4[0], h4[1]);
                const uint32_t p1 = pk_bf16(h4[2], h4[3]);
                *(uint2*)&Grow[32 + 8*m + 2*hi] = make_uint2(p0, p1);
            }

            // out = h @ W_out + b_out (MFMA over H), store float2 from rows c=0,1 (hi==0)
            const bf16x8 H0 = *(const bf16x8*)&Grow[32 + 4*hi];
            const bf16x8 H1 = *(const bf16x8*)&Grow[48 + 4*hi];
            f32x4 oc = zero4;
            oc = __builtin_amdgcn_mfma_f32_16x16x32_bf16(aout[0], H0, oc, 0, 0, 0);
            oc = __builtin_amdgcn_mfma_f32_16x16x32_bf16(aout[1], H1, oc, 0, 0, 0);
            if (h0 && vr[r]) {
                float2 o;
                o.x = (oc[0] + bo0) * mf;
                o.y = (oc[1] + bo1) * mf;
                *(float2*)&out[((size_t)f * N + gi[r]) * 2] = o;
            }

            // write next step's gm_mean (bf16) into words 0..31
            #pragma unroll
            for (int m = 0; m < 4; ++m) {
                const uint32_t p0 = pk_bf16(gm[r][m][0] * invf2, gm[r][m][1] * invf2);
                const uint32_t p1 = pk_bf16(gm[r][m][2] * invf2, gm[r][m][3] * invf2);
                *(uint2*)&Grow[8*m + 2*hi] = make_uint2(p0, p1);
            }
        }
    }

    // ---- final step S-1: zeros ----
    if (t < P) {
        const size_t o = ((size_t)(S_DIM - 1) * N + start + t) * 2;
        out[o] = 0.0f; out[o + 1] = 0.0f;
    }
}

extern "C" void kernel_launch(void* const* d_in, const int* in_sizes, int n_in,
                              void* d_out, int out_size, void* d_ws, size_t ws_size,
                              hipStream_t stream) {
    const float* nodes_abs = (const float*)d_in[0];
    const float* seq_list  = (const float*)d_in[3];
    const int*   pednum    = (const int*)  d_in[5];
    const float* W_in      = (const float*)d_in[6];
    const float* W_gm      = (const float*)d_in[7];
    const float* b_h       = (const float*)d_in[8];
    const float* W_out     = (const float*)d_in[9];
    const float* b_out     = (const float*)d_in[10];
    float*       out       = (float*)d_out;

    const int N = in_sizes[3] / S_DIM;
    const int B = in_sizes[5];

    pfa_kernel<<<B, 256, 0, stream>>>(nodes_abs, seq_list, pednum,
                                      W_in, W_gm, b_h, W_out, b_out,
                                      out, N, B);
}

// Round 5
// 87.634 us; speedup vs baseline: 1.2047x; 1.2047x over previous
//
#include <hip/hip_runtime.h>

#define S_DIM 20
#define NSTEP 19     // S_DIM - 1 compute steps
#define EMB   64
#define GSTR  36     // uint32 words/ped-row: 0..31 bf16 payload (gm_mean, then h, then gm_mean), 4 pad; 36%32==4 -> 2-way (free)
#define MAXP  128

typedef __attribute__((ext_vector_type(8))) short bf16x8;
typedef __attribute__((ext_vector_type(4))) float f32x4;

__device__ __forceinline__ uint32_t pk_bf16(float lo, float hi) {
    uint32_t r;
    asm("v_cvt_pk_bf16_f32 %0, %1, %2" : "=v"(r) : "v"(lo), "v"(hi));
    return r;
}
__device__ __forceinline__ short bf16s(float v) { return (short)(pk_bf16(v, v) & 0xffffu); }
__device__ __forceinline__ float unbf16(uint32_t lo16) {
    union { uint32_t u; float f; } c; c.u = lo16 << 16; return c.f;
}

__global__ __launch_bounds__(512, 4) void pfa_kernel(
    const float* __restrict__ nodes_abs,   // (S,N,2)
    const float* __restrict__ seq_list,    // (S,N)
    const int*   __restrict__ pednum,      // (B)
    const float* __restrict__ W_in,        // (2,EMB)
    const float* __restrict__ W_gm,        // (EMB,EMB)
    const float* __restrict__ b_h,         // (EMB)
    const float* __restrict__ W_out,       // (EMB,2)
    const float* __restrict__ b_out,       // (2)
    float*       __restrict__ out,         // (S,N,2)
    int N, int B)
{
    const int b    = blockIdx.x;
    const int t    = threadIdx.x;
    const int lane = t & 63;
    const int w    = t >> 6;           // 8 waves, one row-block each
    const int l15  = lane & 15;
    const int hi   = lane >> 4;

    __shared__ __attribute__((aligned(16))) uint32_t G[8 * 16 * GSTR];  // 18432 B, wave-private slices
    __shared__ uint32_t masks[MAXP];
    __shared__ float2   cxy[NSTEP];

    // ---- scene start: per-wave redundant prefix sum of pednum ----
    int partial = 0;
    for (int i = lane; i < b; i += 64) partial += pednum[i];
    #pragma unroll
    for (int off = 32; off; off >>= 1) partial += __shfl_xor(partial, off, 64);
    const int start = partial;
    const int P = min(pednum[b], MAXP);
    const int q = (P + 7) >> 3;        // peds per row-block

    // ---- zero own G slice (wave-private) ----
    {
        uint4* g4 = (uint4*)&G[w * 16 * GSTR];
        for (int i = lane; i < 16 * GSTR / 4; i += 64)
            g4[i] = make_uint4(0u, 0u, 0u, 0u);
    }

    // ---- constant A-fragments ----
    // pre-MFMA: D[j][ped] = sum_k W_gm[k][j] * gm_mean[k][ped];  A-frag row j=16m+l15, k=32T+8hi+e
    bf16x8 agm[4][2];
    #pragma unroll
    for (int m = 0; m < 4; ++m)
        #pragma unroll
        for (int T = 0; T < 2; ++T)
            #pragma unroll
            for (int e = 0; e < 8; ++e)
                agm[m][T][e] = bf16s(W_gm[(32*T + 8*hi + e) * EMB + 16*m + l15]);

    // aug A-tile: k rows 0..7 = [w0h,w0l,w0h,w1h,w1l,w1h,bhh,bhl] at column j; rows 8..31 zero
    bf16x8 aaug[4];
    #pragma unroll
    for (int m = 0; m < 4; ++m) {
        bf16x8 a = {0,0,0,0,0,0,0,0};
        if (hi == 0) {
            const int j = 16*m + l15;
            const float w0 = W_in[j], w1 = W_in[EMB + j], bh = b_h[j];
            const short w0h = bf16s(w0); const short w0l = bf16s(w0 - unbf16((uint16_t)w0h));
            const short w1h = bf16s(w1); const short w1l = bf16s(w1 - unbf16((uint16_t)w1h));
            const short bhh = bf16s(bh); const short bhl = bf16s(bh - unbf16((uint16_t)bhh));
            a[0]=w0h; a[1]=w0l; a[2]=w0h; a[3]=w1h; a[4]=w1l; a[5]=w1h; a[6]=bhh; a[7]=bhl;
        }
        aaug[m] = a;
    }

    // out-MFMA: D2[c][ped] = sum_j W_out[j][c] * H[j][ped]; A2 row=c=l15 (only c<2 nonzero), k=j
    bf16x8 aout[2];
    #pragma unroll
    for (int T = 0; T < 2; ++T)
        #pragma unroll
        for (int e = 0; e < 8; ++e) {
            const int j = 32*T + 8*hi + e;
            aout[T][e] = (l15 < 2) ? bf16s(W_out[j*2 + l15]) : (short)0;
        }
    const float bo0 = b_out[0], bo1 = b_out[1];

    // ---- Phase 1: per-ped presence bitmask (prefix-AND over steps) ----
    if (t < P) {
        uint32_t m = 0; bool alive = true;
        #pragma unroll
        for (int f = 0; f < NSTEP; ++f) {
            alive = alive && (seq_list[(size_t)f * N + start + t] > 0.0f);
            m |= (alive ? 1u : 0u) << f;
        }
        masks[t] = m;
    }
    __syncthreads();

    // ---- Phase 2: per-step scene centers (wave w handles f = w, w+8, ...) ----
    for (int f = w; f < NSTEP; f += 8) {
        float cnt = 0.f, sx = 0.f, sy = 0.f;
        for (int p = lane; p < P; p += 64) {
            const float mf = (float)((masks[p] >> f) & 1u);
            const float2 a = *(const float2*)&nodes_abs[((size_t)f * N + start + p) * 2];
            cnt += mf; sx = fmaf(a.x, mf, sx); sy = fmaf(a.y, mf, sy);
        }
        #pragma unroll
        for (int off = 32; off; off >>= 1) {
            cnt += __shfl_xor(cnt, off, 64);
            sx  += __shfl_xor(sx , off, 64);
            sy  += __shfl_xor(sy , off, 64);
        }
        if (lane == 0) {
            const float ic = __builtin_amdgcn_rcpf(fmaxf(cnt, 1.0f));
            cxy[f] = make_float2(sx * ic, sy * ic);
        }
    }
    __syncthreads();

    // ---- Phase 3: sequential loop — no barriers, no shuffles ----
    const int  pd = w * q + l15;
    const bool vr = (l15 < q) && (pd < P);
    const int  gi = start + (vr ? pd : 0);
    const uint32_t mk = vr ? masks[pd] : 0u;
    float2 ab = *(const float2*)&nodes_abs[(size_t)gi * 2];

    uint32_t* const Grow = &G[(w * 16 + l15) * GSTR];
    const bool h0 = (hi == 0);

    f32x4 gm[4];
    const f32x4 zero4 = {0.f, 0.f, 0.f, 0.f};
    #pragma unroll
    for (int m = 0; m < 4; ++m) gm[m] = zero4;

    #pragma unroll 1
    for (int f = 0; f < NSTEP; ++f) {
        const float2 c = cxy[f];
        const float mf  = (float)((mk >> f) & 1u);
        const float cxd = ab.x - c.x;
        const float cyd = ab.y - c.y;
        // prefetch next step's coords (row f+1 always exists: S_DIM rows)
        ab = *(const float2*)&nodes_abs[((size_t)(f + 1) * N + gi) * 2];

        // aug B-fragment in registers (k rows 0..7 live in hi==0 lanes)
        const uint32_t e0 = pk_bf16(cxd, cxd);
        const float    cxl = cxd - unbf16(e0 & 0xffffu);
        const uint32_t ey = pk_bf16(cyd, cyd);
        const float    cyl = cyd - unbf16(ey & 0xffffu);
        const uint32_t e1 = pk_bf16(cxl, cyd);
        const uint32_t e2 = pk_bf16(cyd, cyl);
        union { uint32_t u[4]; bf16x8 v; } b2u;
        b2u.u[0] = h0 ? e0 : 0u;
        b2u.u[1] = h0 ? e1 : 0u;
        b2u.u[2] = h0 ? e2 : 0u;
        b2u.u[3] = h0 ? 0x3f803f80u : 0u;

        // gm_mean B-fragments (words 0..31 of own row)
        const bf16x8 B0 = *(const bf16x8*)&Grow[ 0 + 4*hi];
        const bf16x8 B1 = *(const bf16x8*)&Grow[16 + 4*hi];

        f32x4 acc[4];
        #pragma unroll
        for (int m = 0; m < 4; ++m) {
            f32x4 cacc = zero4;
            cacc = __builtin_amdgcn_mfma_f32_16x16x32_bf16(aaug[m],   b2u.v, cacc, 0, 0, 0);
            cacc = __builtin_amdgcn_mfma_f32_16x16x32_bf16(agm[m][0], B0,    cacc, 0, 0, 0);
            cacc = __builtin_amdgcn_mfma_f32_16x16x32_bf16(agm[m][1], B1,    cacc, 0, 0, 0);
            acc[m] = cacc;
        }

        // tanh (masked) + gm accumulate + write h into words 0..31 (reuse: B0/B1 already consumed)
        const float m2 = -2.0f * mf;
        #pragma unroll
        for (int m = 0; m < 4; ++m) {
            f32x4 h4;
            #pragma unroll
            for (int rr = 0; rr < 4; ++rr) {
                const float x  = acc[m][rr];
                const float e  = __expf(2.0f * x);
                const float tt = __builtin_amdgcn_rcpf(e + 1.0f);
                h4[rr] = fmaf(tt, m2, mf);          // mf * tanh(x)
            }
            gm[m] += h4;
            const uint32_t p0 = pk_bf16(h4[0], h4[1]);
            const uint32_t p1 = pk_bf16(h4[2], h4[3]);
            *(uint2*)&Grow[8*m + 2*hi] = make_uint2(p0, p1);
        }

        // out = (h @ W_out + b_out) * mf via MFMA over H
        const bf16x8 H0 = *(const bf16x8*)&Grow[ 0 + 4*hi];
        const bf16x8 H1 = *(const bf16x8*)&Grow[16 + 4*hi];
        f32x4 oc = zero4;
        oc = __builtin_amdgcn_mfma_f32_16x16x32_bf16(aout[0], H0, oc, 0, 0, 0);
        oc = __builtin_amdgcn_mfma_f32_16x16x32_bf16(aout[1], H1, oc, 0, 0, 0);
        if (h0 && vr) {
            float2 o;
            o.x = (oc[0] + bo0) * mf;
            o.y = (oc[1] + bo1) * mf;
            *(float2*)&out[((size_t)f * N + gi) * 2] = o;
        }

        // write next step's gm_mean (bf16) back into words 0..31 (after H reads)
        const float invf2 = __builtin_amdgcn_rcpf((float)(f + 1));
        #pragma unroll
        for (int m = 0; m < 4; ++m) {
            const uint32_t p0 = pk_bf16(gm[m][0] * invf2, gm[m][1] * invf2);
            const uint32_t p1 = pk_bf16(gm[m][2] * invf2, gm[m][3] * invf2);
            *(uint2*)&Grow[8*m + 2*hi] = make_uint2(p0, p1);
        }
    }

    // ---- final step S-1: zeros ----
    if (t < P) {
        const size_t o = ((size_t)(S_DIM - 1) * N + start + t) * 2;
        out[o] = 0.0f; out[o + 1] = 0.0f;
    }
}

extern "C" void kernel_launch(void* const* d_in, const int* in_sizes, int n_in,
                              void* d_out, int out_size, void* d_ws, size_t ws_size,
                              hipStream_t stream) {
    const float* nodes_abs = (const float*)d_in[0];
    const float* seq_list  = (const float*)d_in[3];
    const int*   pednum    = (const int*)  d_in[5];
    const float* W_in      = (const float*)d_in[6];
    const float* W_gm      = (const float*)d_in[7];
    const float* b_h       = (const float*)d_in[8];
    const float* W_out     = (const float*)d_in[9];
    const float* b_out     = (const float*)d_in[10];
    float*       out       = (float*)d_out;

    const int N = in_sizes[3] / S_DIM;
    const int B = in_sizes[5];

    pfa_kernel<<<B, 512, 0, stream>>>(nodes_abs, seq_list, pednum,
                                      W_in, W_gm, b_h, W_out, b_out,
                                      out, N, B);
}